// Round 8
// baseline (901.259 us; speedup 1.0000x reference)
//
#include <hip/hip_runtime.h>
#include <math.h>

// Shapes (fixed for this problem)
#define HT   128
#define WD   128
#define HW   16384      // HT*WD
#define NB_B 4
#define BHW  65536      // NB_B*HW
#define CD   96
#define C3   288
#define NH   6
#define HD   16
#define HID  255
#define HID2 510
#define KK   7
#define NNB  49
// natten LDS tile
#define LRD  22         // halo tile side (16 + 6)
#define NFR  484        // 22*22 fragments
#define FPAD 20         // padded fragment stride in floats (80 B, 16B-aligned)

// ---------------------------------------------------------------------------
// Fold LayerNorm affine into the following 1x1 conv, and store weights
// TRANSPOSED (wT[c*OS + o]).  Also transposes proj_w and pout_w.
// ---------------------------------------------------------------------------
__global__ __launch_bounds__(256) void prep_weights(
    const float* __restrict__ qkv_w, const float* __restrict__ qkv_b,
    const float* __restrict__ ln1_w, const float* __restrict__ ln1_b,
    const float* __restrict__ pin_w, const float* __restrict__ ln2_w,
    const float* __restrict__ ln2_b,
    const float* __restrict__ proj_w, const float* __restrict__ pout_w,
    float* __restrict__ w1t, float* __restrict__ s1, float* __restrict__ b1,
    float* __restrict__ w2t, float* __restrict__ s2, float* __restrict__ b2,
    float* __restrict__ wpt, float* __restrict__ wot)
{
    int o = blockIdx.x * 256 + threadIdx.x;          // [0, 512)
    if (o < C3) {
        float s = 0.f, bb = qkv_b[o];
        for (int c = 0; c < CD; ++c) {
            float wv = qkv_w[o*CD+c] * ln1_w[c];
            w1t[(size_t)c * C3 + o] = wv;
            s += wv;
            bb += qkv_w[o*CD+c] * ln1_b[c];
        }
        s1[o] = s; b1[o] = bb;
    }
    if (o < HID2) {
        float s = 0.f, bb = 0.f;                     // pin conv has no bias
        for (int c = 0; c < CD; ++c) {
            float wv = pin_w[o*CD+c] * ln2_w[c];
            w2t[(size_t)c * 512 + o] = wv;
            s += wv;
            bb += pin_w[o*CD+c] * ln2_b[c];
        }
        s2[o] = s; b2[o] = bb;
    } else if (o < 512) {                            // pad cols 510/511
        for (int c = 0; c < CD; ++c) w2t[(size_t)c * 512 + o] = 0.f;
        s2[o] = 0.f; b2[o] = 0.f;
    }
    if (o < CD) {
        for (int c = 0; c < CD; ++c)
            wpt[(size_t)c * CD + o] = proj_w[o*CD + c];
        for (int c = 0; c < HID; ++c)
            wot[(size_t)c * CD + o] = pout_w[o*HID + c];
    }
}

// Per-pixel LayerNorm stats (biased variance, eps 1e-5), 4 pixels/thread.
__global__ __launch_bounds__(256) void ln_stats(
    const float* __restrict__ x, float* __restrict__ mu, float* __restrict__ rsig)
{
    int t  = blockIdx.x * 256 + threadIdx.x;
    int p4 = t * 4;
    int b = p4 >> 14, p = p4 & (HW - 1);
    const float* xp = x + (size_t)b * CD * HW + p;
    float4 s = {0.f,0.f,0.f,0.f}, s2 = {0.f,0.f,0.f,0.f};
    #pragma unroll 4
    for (int c = 0; c < CD; ++c) {
        float4 v = *(const float4*)(xp + (size_t)c * HW);
        s.x += v.x; s.y += v.y; s.z += v.z; s.w += v.w;
        s2.x = fmaf(v.x, v.x, s2.x); s2.y = fmaf(v.y, v.y, s2.y);
        s2.z = fmaf(v.z, v.z, s2.z); s2.w = fmaf(v.w, v.w, s2.w);
    }
    const float inv = 1.f / CD;
    float4 m, r;
    m.x = s.x*inv; m.y = s.y*inv; m.z = s.z*inv; m.w = s.w*inv;
    r.x = rsqrtf(s2.x*inv - m.x*m.x + 1e-5f);
    r.y = rsqrtf(s2.y*inv - m.y*m.y + 1e-5f);
    r.z = rsqrtf(s2.z*inv - m.z*m.z + 1e-5f);
    r.w = rsqrtf(s2.w*inv - m.w*m.w + 1e-5f);
    *(float4*)(mu + p4)   = m;
    *(float4*)(rsig + p4) = r;
}

// ---------------------------------------------------------------------------
// 1x1 conv (vector ALU GEMM). 4 pixels x 16 couts / thread.
// ---------------------------------------------------------------------------
template<int EPI>
__global__ __launch_bounds__(256) void conv1x1(
    const float* __restrict__ in, const float* __restrict__ wT,
    int Cin, int Cout, int OS,
    const float* __restrict__ S, const float* __restrict__ Bb,
    const float* __restrict__ mu, const float* __restrict__ rsig,
    const float* __restrict__ res, const float* __restrict__ scale,
    float* __restrict__ out)
{
    int t  = blockIdx.y * 256 + threadIdx.x;
    int p4 = t * 4;
    int o0 = blockIdx.x * 16;
    int b = p4 >> 14, p = p4 & (HW - 1);
    const float* ip = in + (size_t)b * Cin * HW + p;
    float4 acc[16];
    #pragma unroll
    for (int u = 0; u < 16; ++u) acc[u] = {0.f,0.f,0.f,0.f};
    #pragma unroll 2
    for (int c = 0; c < Cin; ++c) {
        float4 v = *(const float4*)(ip + (size_t)c * HW);
        const float* wr = wT + (size_t)c * OS + o0;
        #pragma unroll
        for (int u = 0; u < 16; ++u) {
            float wv = wr[u];
            acc[u].x = fmaf(v.x, wv, acc[u].x);
            acc[u].y = fmaf(v.y, wv, acc[u].y);
            acc[u].z = fmaf(v.z, wv, acc[u].z);
            acc[u].w = fmaf(v.w, wv, acc[u].w);
        }
    }
    size_t obase = (size_t)b * Cout * HW + p;
    if (EPI == 0) {
        float4 m = *(const float4*)(mu + p4);
        float4 r = *(const float4*)(rsig + p4);
        #pragma unroll
        for (int u = 0; u < 16; ++u) {
            int o = o0 + u;
            if (o < Cout) {
                float so = S[o], bo = Bb[o];
                float4 ov;
                ov.x = r.x * (acc[u].x - m.x * so) + bo;
                ov.y = r.y * (acc[u].y - m.y * so) + bo;
                ov.z = r.z * (acc[u].z - m.z * so) + bo;
                ov.w = r.w * (acc[u].w - m.w * so) + bo;
                *(float4*)(out + obase + (size_t)o * HW) = ov;
            }
        }
    } else if (EPI == 1) {
        #pragma unroll
        for (int u = 0; u < 16; ++u) {
            int o = o0 + u;
            float bo = Bb[o], sc = scale[o];
            float4 rv = *(const float4*)(res + obase + (size_t)o * HW);
            float4 ov;
            ov.x = rv.x + (acc[u].x + bo) * sc;
            ov.y = rv.y + (acc[u].y + bo) * sc;
            ov.z = rv.z + (acc[u].z + bo) * sc;
            ov.w = rv.w + (acc[u].w + bo) * sc;
            *(float4*)(out + obase + (size_t)o * HW) = ov;
        }
    } else {
        #pragma unroll
        for (int u = 0; u < 16; ++u) {
            int o = o0 + u;
            float sc = scale[o];
            float4 rv = *(const float4*)(res + obase + (size_t)o * HW);
            float4 ov;
            ov.x = rv.x + acc[u].x * sc;
            ov.y = rv.y + acc[u].y * sc;
            ov.z = rv.z + acc[u].z * sc;
            ov.w = rv.w + acc[u].w * sc;
            *(float4*)(out + obase + (size_t)o * HW) = ov;
        }
    }
}

// ---------------------------------------------------------------------------
// Depthwise 3x3 + bias for one head group (q, k, or v), output TRANSPOSED to
// [b][head][px][16].  NORM=true l2-normalizes the fragment (K path).
// ---------------------------------------------------------------------------
template<bool NORM>
__global__ __launch_bounds__(256) void dwconv_t(
    const float* __restrict__ in, const float* __restrict__ dwv,
    const float* __restrict__ bias, float* __restrict__ outt, int cbase)
{
    int t  = blockIdx.x * 256 + threadIdx.x;
    int p4 = t * 4;
    int bh = blockIdx.y;                       // b*NH + head
    int b = bh / NH, head = bh % NH;
    int h = p4 >> 7, wx = p4 & (WD - 1);
    float4 acc[16];
    #pragma unroll
    for (int hd = 0; hd < 16; ++hd) {
        int c = cbase + head * HD + hd;
        const float* ip = in + ((size_t)b * C3 + c) * HW;
        const float* wk = dwv + c * 9;
        float bz = bias[c];
        float a0 = bz, a1 = bz, a2 = bz, a3 = bz;
        #pragma unroll
        for (int ky = 0; ky < 3; ++ky) {
            int hh = h + ky - 1;
            if (hh < 0 || hh >= HT) continue;
            const float* rowp = ip + hh * WD + wx;
            float vm = (wx > 0)      ? rowp[-1] : 0.f;
            float4 v = *(const float4*)rowp;
            float vp = (wx + 4 < WD) ? rowp[4]  : 0.f;
            float w0 = wk[ky*3+0], w1 = wk[ky*3+1], w2 = wk[ky*3+2];
            a0 = fmaf(vm,  w0, a0); a0 = fmaf(v.x, w1, a0); a0 = fmaf(v.y, w2, a0);
            a1 = fmaf(v.x, w0, a1); a1 = fmaf(v.y, w1, a1); a1 = fmaf(v.z, w2, a1);
            a2 = fmaf(v.y, w0, a2); a2 = fmaf(v.z, w1, a2); a2 = fmaf(v.w, w2, a2);
            a3 = fmaf(v.z, w0, a3); a3 = fmaf(v.w, w1, a3); a3 = fmaf(vp,  w2, a3);
        }
        acc[hd] = {a0, a1, a2, a3};
    }
    if (NORM) {
        float n0=0.f, n1=0.f, n2=0.f, n3=0.f;
        #pragma unroll
        for (int hd = 0; hd < 16; ++hd) {
            n0 = fmaf(acc[hd].x, acc[hd].x, n0);
            n1 = fmaf(acc[hd].y, acc[hd].y, n1);
            n2 = fmaf(acc[hd].z, acc[hd].z, n2);
            n3 = fmaf(acc[hd].w, acc[hd].w, n3);
        }
        n0 = 1.f / fmaxf(sqrtf(n0), 1e-12f);
        n1 = 1.f / fmaxf(sqrtf(n1), 1e-12f);
        n2 = 1.f / fmaxf(sqrtf(n2), 1e-12f);
        n3 = 1.f / fmaxf(sqrtf(n3), 1e-12f);
        #pragma unroll
        for (int hd = 0; hd < 16; ++hd) {
            acc[hd].x *= n0; acc[hd].y *= n1; acc[hd].z *= n2; acc[hd].w *= n3;
        }
    }
    float* op = outt + ((size_t)bh * HW + p4) * 16;
#define STORE_PX(pi, comp)                                                    \
    {                                                                         \
        float4 w0 = {acc[ 0].comp, acc[ 1].comp, acc[ 2].comp, acc[ 3].comp}; \
        float4 w1 = {acc[ 4].comp, acc[ 5].comp, acc[ 6].comp, acc[ 7].comp}; \
        float4 w2 = {acc[ 8].comp, acc[ 9].comp, acc[10].comp, acc[11].comp}; \
        float4 w3 = {acc[12].comp, acc[13].comp, acc[14].comp, acc[15].comp}; \
        *(float4*)(op + pi*16 +  0) = w0;                                     \
        *(float4*)(op + pi*16 +  4) = w1;                                     \
        *(float4*)(op + pi*16 +  8) = w2;                                     \
        *(float4*)(op + pi*16 + 12) = w3;                                     \
    }
    STORE_PX(0, x) STORE_PX(1, y) STORE_PX(2, z) STORE_PX(3, w)
#undef STORE_PX
}

// FFN depthwise 3x3 (no bias) fused with exact-GELU gating, 4 pixels/thread.
__global__ __launch_bounds__(256) void dw_gate(
    const float* __restrict__ in, const float* __restrict__ dwv,
    float* __restrict__ out)
{
    int t  = blockIdx.x * 256 + threadIdx.x;
    int p4 = t * 4;
    int bj = blockIdx.y;
    int b = bj / HID, j = bj % HID;
    int h = p4 >> 7, wx = p4 & (WD - 1);
    const float* i1 = in + ((size_t)b * HID2 + j) * HW;
    const float* i2 = i1 + (size_t)HID * HW;
    const float* wk1 = dwv + j * 9;
    const float* wk2 = dwv + (j + HID) * 9;
    float a0=0.f,a1=0.f,a2=0.f,a3=0.f, g0=0.f,g1=0.f,g2=0.f,g3=0.f;
    #pragma unroll
    for (int ky = 0; ky < 3; ++ky) {
        int hh = h + ky - 1;
        if (hh < 0 || hh >= HT) continue;
        const float* r1 = i1 + hh * WD + wx;
        const float* r2 = i2 + hh * WD + wx;
        bool lm = (wx > 0), rp = (wx + 4 < WD);
        float um = lm ? r1[-1] : 0.f;
        float4 u = *(const float4*)r1;
        float up = rp ? r1[4] : 0.f;
        float vm = lm ? r2[-1] : 0.f;
        float4 v = *(const float4*)r2;
        float vp = rp ? r2[4] : 0.f;
        float w10 = wk1[ky*3+0], w11 = wk1[ky*3+1], w12 = wk1[ky*3+2];
        float w20 = wk2[ky*3+0], w21 = wk2[ky*3+1], w22 = wk2[ky*3+2];
        a0 = fmaf(um,  w10, a0); a0 = fmaf(u.x, w11, a0); a0 = fmaf(u.y, w12, a0);
        a1 = fmaf(u.x, w10, a1); a1 = fmaf(u.y, w11, a1); a1 = fmaf(u.z, w12, a1);
        a2 = fmaf(u.y, w10, a2); a2 = fmaf(u.z, w11, a2); a2 = fmaf(u.w, w12, a2);
        a3 = fmaf(u.z, w10, a3); a3 = fmaf(u.w, w11, a3); a3 = fmaf(up,  w12, a3);
        g0 = fmaf(vm,  w20, g0); g0 = fmaf(v.x, w21, g0); g0 = fmaf(v.y, w22, g0);
        g1 = fmaf(v.x, w20, g1); g1 = fmaf(v.y, w21, g1); g1 = fmaf(v.z, w22, g1);
        g2 = fmaf(v.y, w20, g2); g2 = fmaf(v.z, w21, g2); g2 = fmaf(v.w, w22, g2);
        g3 = fmaf(v.z, w20, g3); g3 = fmaf(v.w, w21, g3); g3 = fmaf(vp,  w22, g3);
    }
    const float is2 = 0.70710678118654752f;
    float4 ov;
    ov.x = 0.5f * a0 * (1.f + erff(a0 * is2)) * g0;
    ov.y = 0.5f * a1 * (1.f + erff(a1 * is2)) * g1;
    ov.z = 0.5f * a2 * (1.f + erff(a2 * is2)) * g2;
    ov.w = 0.5f * a3 * (1.f + erff(a3 * is2)) * g3;
    *(float4*)(out + ((size_t)b * HID + j) * HW + p4) = ov;
}

// ---------------------------------------------------------------------------
// Neighborhood attention with LDS-staged K/V tiles.
// Block = 16x16 queries, one (b,head).  Stage the 22x22-fragment halo tile of
// K into LDS (coalesced float4), compute scores from LDS; re-stage V into the
// SAME buffer; compute AV.  Fragment stride padded to 20 floats (16B-aligned
// for ds_read_b128, banks spread).  All neighbor reads are ds_read_b128 at
// compile-time immediate offsets.
// ---------------------------------------------------------------------------
__global__ __launch_bounds__(256) void natten(
    const float* __restrict__ qt, const float* __restrict__ kt,
    const float* __restrict__ vt, const float* __restrict__ rpb,
    const float* __restrict__ temp, float* __restrict__ out)
{
    __shared__ __align__(16) float skv[NFR * FPAD];   // 38,720 B
    __shared__ float srpb[169];
    int bh = blockIdx.z;
    int b = bh / NH, head = bh % NH;
    float T = temp[head];
    if (threadIdx.x < 169) srpb[threadIdx.x] = rpb[head * 169 + threadIdx.x] * T;

    int i0 = blockIdx.y * 16, j0 = blockIdx.x * 16;
    int r0 = min(max(i0 - 3, 0), HT - LRD);
    int c0 = min(max(j0 - 3, 0), WD - LRD);
    const float4* ktb = (const float4*)(kt + (size_t)bh * HW * 16);
    const float4* vtb = (const float4*)(vt + (size_t)bh * HW * 16);

    // ---- stage K (1936 float4s, coalesced) ----
    #pragma unroll
    for (int k = 0; k < 8; ++k) {
        int g = threadIdx.x + k * 256;
        if (g < NFR * 4) {
            int fg = g >> 2, sub = g & 3;
            int fr = fg / LRD, fc = fg - fr * LRD;
            float4 v = ktb[(size_t)((r0 + fr) * WD + (c0 + fc)) * 4 + sub];
            *(float4*)(&skv[fg * FPAD + sub * 4]) = v;
        }
    }

    int i = i0 + (threadIdx.x >> 4);
    int j = j0 + (threadIdx.x & 15);

    // q fragment (pixel-major) + l2 norm + temperature (overlaps staging)
    const float* qp = qt + ((size_t)bh * HW + (size_t)(i * WD + j)) * 16;
    float4 q0 = *(const float4*)(qp + 0);
    float4 q1 = *(const float4*)(qp + 4);
    float4 q2 = *(const float4*)(qp + 8);
    float4 q3 = *(const float4*)(qp + 12);
    float qn = 0.f;
    qn = fmaf(q0.x,q0.x,qn); qn = fmaf(q0.y,q0.y,qn); qn = fmaf(q0.z,q0.z,qn); qn = fmaf(q0.w,q0.w,qn);
    qn = fmaf(q1.x,q1.x,qn); qn = fmaf(q1.y,q1.y,qn); qn = fmaf(q1.z,q1.z,qn); qn = fmaf(q1.w,q1.w,qn);
    qn = fmaf(q2.x,q2.x,qn); qn = fmaf(q2.y,q2.y,qn); qn = fmaf(q2.z,q2.z,qn); qn = fmaf(q2.w,q2.w,qn);
    qn = fmaf(q3.x,q3.x,qn); qn = fmaf(q3.y,q3.y,qn); qn = fmaf(q3.z,q3.z,qn); qn = fmaf(q3.w,q3.w,qn);
    qn = T / fmaxf(sqrtf(qn), 1e-12f);
    q0.x*=qn; q0.y*=qn; q0.z*=qn; q0.w*=qn;
    q1.x*=qn; q1.y*=qn; q1.z*=qn; q1.w*=qn;
    q2.x*=qn; q2.y*=qn; q2.z*=qn; q2.w*=qn;
    q3.x*=qn; q3.y*=qn; q3.z*=qn; q3.w*=qn;

    int ri0 = min(max(i - 3, 0), HT - KK);
    int cj0 = min(max(j - 3, 0), WD - KK);
    int bi0 = i - ri0 + 6, bj0 = j - cj0 + 6;
    const float* fb = &skv[((ri0 - r0) * LRD + (cj0 - c0)) * FPAD];

    __syncthreads();                    // K (and srpb) staged

    // ---- pass 1: scores from LDS ----
    float s[NNB]; float m = -1e30f;
    #pragma unroll
    for (int o = 0; o < NNB; ++o) {
        const float* kk = fb + ((o / KK) * LRD + (o % KK)) * FPAD;
        float4 k0 = *(const float4*)(kk + 0);
        float4 k1 = *(const float4*)(kk + 4);
        float4 k2 = *(const float4*)(kk + 8);
        float4 k3 = *(const float4*)(kk + 12);
        float d = 0.f;
        d = fmaf(q0.x,k0.x,d); d = fmaf(q0.y,k0.y,d); d = fmaf(q0.z,k0.z,d); d = fmaf(q0.w,k0.w,d);
        d = fmaf(q1.x,k1.x,d); d = fmaf(q1.y,k1.y,d); d = fmaf(q1.z,k1.z,d); d = fmaf(q1.w,k1.w,d);
        d = fmaf(q2.x,k2.x,d); d = fmaf(q2.y,k2.y,d); d = fmaf(q2.z,k2.z,d); d = fmaf(q2.w,k2.w,d);
        d = fmaf(q3.x,k3.x,d); d = fmaf(q3.y,k3.y,d); d = fmaf(q3.z,k3.z,d); d = fmaf(q3.w,k3.w,d);
        float sv = d + srpb[(bi0 - o / KK) * 13 + (bj0 - o % KK)];
        s[o] = sv;
        m = fmaxf(m, sv);
    }
    __syncthreads();                    // all waves done reading K

    // ---- stage V into the same buffer; softmax VALU overlaps ----
    #pragma unroll
    for (int k = 0; k < 8; ++k) {
        int g = threadIdx.x + k * 256;
        if (g < NFR * 4) {
            int fg = g >> 2, sub = g & 3;
            int fr = fg / LRD, fc = fg - fr * LRD;
            float4 v = vtb[(size_t)((r0 + fr) * WD + (c0 + fc)) * 4 + sub];
            *(float4*)(&skv[fg * FPAD + sub * 4]) = v;
        }
    }
    float l = 0.f;
    #pragma unroll
    for (int o = 0; o < NNB; ++o) { float pv = __expf(s[o] - m); s[o] = pv; l += pv; }
    float inv = 1.f / l;
    __syncthreads();                    // V staged

    // ---- pass 3: AV from LDS ----
    float4 a0 = {0.f,0.f,0.f,0.f}, a1 = a0, a2 = a0, a3 = a0;
    #pragma unroll
    for (int o = 0; o < NNB; ++o) {
        const float* vvp = fb + ((o / KK) * LRD + (o % KK)) * FPAD;
        float4 v0 = *(const float4*)(vvp + 0);
        float4 v1 = *(const float4*)(vvp + 4);
        float4 v2 = *(const float4*)(vvp + 8);
        float4 v3 = *(const float4*)(vvp + 12);
        float pv = s[o];
        a0.x = fmaf(pv, v0.x, a0.x); a0.y = fmaf(pv, v0.y, a0.y);
        a0.z = fmaf(pv, v0.z, a0.z); a0.w = fmaf(pv, v0.w, a0.w);
        a1.x = fmaf(pv, v1.x, a1.x); a1.y = fmaf(pv, v1.y, a1.y);
        a1.z = fmaf(pv, v1.z, a1.z); a1.w = fmaf(pv, v1.w, a1.w);
        a2.x = fmaf(pv, v2.x, a2.x); a2.y = fmaf(pv, v2.y, a2.y);
        a2.z = fmaf(pv, v2.z, a2.z); a2.w = fmaf(pv, v2.w, a2.w);
        a3.x = fmaf(pv, v3.x, a3.x); a3.y = fmaf(pv, v3.y, a3.y);
        a3.z = fmaf(pv, v3.z, a3.z); a3.w = fmaf(pv, v3.w, a3.w);
    }
    float* op = out + ((size_t)b * CD + head * HD) * HW + i * WD + j;
    op[(size_t) 0*HW] = a0.x*inv; op[(size_t) 1*HW] = a0.y*inv;
    op[(size_t) 2*HW] = a0.z*inv; op[(size_t) 3*HW] = a0.w*inv;
    op[(size_t) 4*HW] = a1.x*inv; op[(size_t) 5*HW] = a1.y*inv;
    op[(size_t) 6*HW] = a1.z*inv; op[(size_t) 7*HW] = a1.w*inv;
    op[(size_t) 8*HW] = a2.x*inv; op[(size_t) 9*HW] = a2.y*inv;
    op[(size_t)10*HW] = a2.z*inv; op[(size_t)11*HW] = a2.w*inv;
    op[(size_t)12*HW] = a3.x*inv; op[(size_t)13*HW] = a3.y*inv;
    op[(size_t)14*HW] = a3.z*inv; op[(size_t)15*HW] = a3.w*inv;
}

// ---------------------------------------------------------------------------
extern "C" void kernel_launch(void* const* d_in, const int* in_sizes, int n_in,
                              void* d_out, int out_size, void* d_ws, size_t ws_size,
                              hipStream_t stream)
{
    const float* x        = (const float*)d_in[0];
    const float* ln1_w    = (const float*)d_in[1];
    const float* ln1_b    = (const float*)d_in[2];
    const float* qkv_w    = (const float*)d_in[3];
    const float* qkv_b    = (const float*)d_in[4];
    const float* qkv_dw_w = (const float*)d_in[5];
    const float* qkv_dw_b = (const float*)d_in[6];
    const float* rpb      = (const float*)d_in[7];
    const float* temp     = (const float*)d_in[8];
    const float* proj_w   = (const float*)d_in[9];
    const float* proj_b   = (const float*)d_in[10];
    const float* ln2_w    = (const float*)d_in[11];
    const float* ln2_b    = (const float*)d_in[12];
    const float* pin_w    = (const float*)d_in[13];
    const float* dw_w     = (const float*)d_in[14];
    const float* pout_w   = (const float*)d_in[15];
    const float* beta     = (const float*)d_in[16];
    const float* gamma    = (const float*)d_in[17];
    float* out = (float*)d_out;
    float* f   = (float*)d_ws;
    (void)in_sizes; (void)n_in; (void)out_size; (void)ws_size;

    // workspace layout (floats)
    float* W1T = f;                  // 27648
    float* W2T = W1T + 27648;        // 49152
    float* WPT = W2T + 49152;        // 9216
    float* WOT = WPT + 9216;         // 24480
    float* S1  = WOT + 24480;        // 512 each
    float* B1  = S1 + 512;
    float* S2  = B1 + 512;
    float* B2  = S2 + 512;
    float* MU  = B2 + 512;           // 65536
    float* RS  = MU + 65536;         // 65536
    float* A   = f + 262144;
    float* QKV = A;                  // 18,874,368 qkv_pre; later ffn_pre
    float* QT  = A + 18874368;       //  6,291,456 q, transposed [bh][px][16]
    float* KT  = QT + 6291456;       //  6,291,456 K, transposed+normalized
    float* VT  = KT + 6291456;       //  6,291,456 V, transposed
    float* AO  = A + 37748736;       //  6,291,456 attn out; later gated (16.7M)
    float* X2  = A + 54460416;       //  6,291,456 post-attention residual

    // 1. fold LN1/LN2 into conv weights; transpose all conv weights
    prep_weights<<<dim3(2), dim3(256), 0, stream>>>(
        qkv_w, qkv_b, ln1_w, ln1_b, pin_w, ln2_w, ln2_b, proj_w, pout_w,
        W1T, S1, B1, W2T, S2, B2, WPT, WOT);
    // 2. LN1 stats
    ln_stats<<<dim3(64), dim3(256), 0, stream>>>(x, MU, RS);
    // 3. qkv_pre = conv1x1(LN1(x))  [B,288,HW]
    conv1x1<0><<<dim3(18, 64), dim3(256), 0, stream>>>(
        x, W1T, CD, C3, C3, S1, B1, MU, RS, nullptr, nullptr, QKV);
    // 4. depthwise 3x3 + bias; q/k/v all transposed to [bh][px][16] (K normed)
    dwconv_t<false><<<dim3(16, NB_B * NH), dim3(256), 0, stream>>>(
        QKV, qkv_dw_w, qkv_dw_b, QT, 0);
    dwconv_t<true><<<dim3(16, NB_B * NH), dim3(256), 0, stream>>>(
        QKV, qkv_dw_w, qkv_dw_b, KT, CD);
    dwconv_t<false><<<dim3(16, NB_B * NH), dim3(256), 0, stream>>>(
        QKV, qkv_dw_w, qkv_dw_b, VT, 2 * CD);
    // 5. neighborhood attention (LDS-staged) -> [B,96,HW]
    natten<<<dim3(8, 8, NB_B * NH), dim3(256), 0, stream>>>(
        QT, KT, VT, rpb, temp, AO);
    // 6. x2 = x + (proj(attn)+proj_b)*beta
    conv1x1<1><<<dim3(6, 64), dim3(256), 0, stream>>>(
        AO, WPT, CD, CD, CD, nullptr, proj_b, nullptr, nullptr, x, beta, X2);
    // 7. LN2 stats
    ln_stats<<<dim3(64), dim3(256), 0, stream>>>(X2, MU, RS);
    // 8. ffn_pre = conv1x1(LN2(x2))  [B,510,HW]
    conv1x1<0><<<dim3(32, 64), dim3(256), 0, stream>>>(
        X2, W2T, CD, HID2, 512, S2, B2, MU, RS, nullptr, nullptr, QKV);
    // 9. gated = gelu(dw(x1)) * dw(x2)  [B,255,HW]
    dw_gate<<<dim3(16, NB_B * HID), dim3(256), 0, stream>>>(QKV, dw_w, AO);
    // 10. out = x2 + pout(gated)*gamma
    conv1x1<2><<<dim3(6, 64), dim3(256), 0, stream>>>(
        AO, WOT, HID, CD, CD, nullptr, nullptr, nullptr, nullptr, X2, gamma, out);
}

// Round 11
// 794.650 us; speedup vs baseline: 1.1342x; 1.1342x over previous
//
#include <hip/hip_runtime.h>
#include <math.h>

// Shapes (fixed for this problem)
#define HT   128
#define WD   128
#define HW   16384      // HT*WD
#define NB_B 4
#define BHW  65536      // NB_B*HW
#define CD   96
#define C3   288
#define NH   6
#define HD   16
#define HID  255
#define HID2 510
#define KK   7
#define NNB  49
// natten LDS tile
#define LRD  22         // halo tile side (16 + 6)
#define NFR  484        // 22*22 fragments

// ---------------------------------------------------------------------------
// Fold LayerNorm affine into the following 1x1 conv, and store weights
// TRANSPOSED (wT[c*OS + o]).  Also transposes proj_w and pout_w.
// ---------------------------------------------------------------------------
__global__ __launch_bounds__(256) void prep_weights(
    const float* __restrict__ qkv_w, const float* __restrict__ qkv_b,
    const float* __restrict__ ln1_w, const float* __restrict__ ln1_b,
    const float* __restrict__ pin_w, const float* __restrict__ ln2_w,
    const float* __restrict__ ln2_b,
    const float* __restrict__ proj_w, const float* __restrict__ pout_w,
    float* __restrict__ w1t, float* __restrict__ s1, float* __restrict__ b1,
    float* __restrict__ w2t, float* __restrict__ s2, float* __restrict__ b2,
    float* __restrict__ wpt, float* __restrict__ wot)
{
    int o = blockIdx.x * 256 + threadIdx.x;          // [0, 512)
    if (o < C3) {
        float s = 0.f, bb = qkv_b[o];
        for (int c = 0; c < CD; ++c) {
            float wv = qkv_w[o*CD+c] * ln1_w[c];
            w1t[(size_t)c * C3 + o] = wv;
            s += wv;
            bb += qkv_w[o*CD+c] * ln1_b[c];
        }
        s1[o] = s; b1[o] = bb;
    }
    if (o < HID2) {
        float s = 0.f, bb = 0.f;                     // pin conv has no bias
        for (int c = 0; c < CD; ++c) {
            float wv = pin_w[o*CD+c] * ln2_w[c];
            w2t[(size_t)c * 512 + o] = wv;
            s += wv;
            bb += pin_w[o*CD+c] * ln2_b[c];
        }
        s2[o] = s; b2[o] = bb;
    } else if (o < 512) {                            // pad cols 510/511
        for (int c = 0; c < CD; ++c) w2t[(size_t)c * 512 + o] = 0.f;
        s2[o] = 0.f; b2[o] = 0.f;
    }
    if (o < CD) {
        for (int c = 0; c < CD; ++c)
            wpt[(size_t)c * CD + o] = proj_w[o*CD + c];
        for (int c = 0; c < HID; ++c)
            wot[(size_t)c * CD + o] = pout_w[o*HID + c];
    }
}

// Per-pixel LayerNorm stats (biased variance, eps 1e-5), 4 pixels/thread.
__global__ __launch_bounds__(256) void ln_stats(
    const float* __restrict__ x, float* __restrict__ mu, float* __restrict__ rsig)
{
    int t  = blockIdx.x * 256 + threadIdx.x;
    int p4 = t * 4;
    int b = p4 >> 14, p = p4 & (HW - 1);
    const float* xp = x + (size_t)b * CD * HW + p;
    float4 s = {0.f,0.f,0.f,0.f}, s2 = {0.f,0.f,0.f,0.f};
    #pragma unroll 4
    for (int c = 0; c < CD; ++c) {
        float4 v = *(const float4*)(xp + (size_t)c * HW);
        s.x += v.x; s.y += v.y; s.z += v.z; s.w += v.w;
        s2.x = fmaf(v.x, v.x, s2.x); s2.y = fmaf(v.y, v.y, s2.y);
        s2.z = fmaf(v.z, v.z, s2.z); s2.w = fmaf(v.w, v.w, s2.w);
    }
    const float inv = 1.f / CD;
    float4 m, r;
    m.x = s.x*inv; m.y = s.y*inv; m.z = s.z*inv; m.w = s.w*inv;
    r.x = rsqrtf(s2.x*inv - m.x*m.x + 1e-5f);
    r.y = rsqrtf(s2.y*inv - m.y*m.y + 1e-5f);
    r.z = rsqrtf(s2.z*inv - m.z*m.z + 1e-5f);
    r.w = rsqrtf(s2.w*inv - m.w*m.w + 1e-5f);
    *(float4*)(mu + p4)   = m;
    *(float4*)(rsig + p4) = r;
}

// ---------------------------------------------------------------------------
// 1x1 conv (vector ALU GEMM). 4 pixels x 16 couts / thread.
// ---------------------------------------------------------------------------
template<int EPI>
__global__ __launch_bounds__(256) void conv1x1(
    const float* __restrict__ in, const float* __restrict__ wT,
    int Cin, int Cout, int OS,
    const float* __restrict__ S, const float* __restrict__ Bb,
    const float* __restrict__ mu, const float* __restrict__ rsig,
    const float* __restrict__ res, const float* __restrict__ scale,
    float* __restrict__ out)
{
    int t  = blockIdx.y * 256 + threadIdx.x;
    int p4 = t * 4;
    int o0 = blockIdx.x * 16;
    int b = p4 >> 14, p = p4 & (HW - 1);
    const float* ip = in + (size_t)b * Cin * HW + p;
    float4 acc[16];
    #pragma unroll
    for (int u = 0; u < 16; ++u) acc[u] = {0.f,0.f,0.f,0.f};
    #pragma unroll 2
    for (int c = 0; c < Cin; ++c) {
        float4 v = *(const float4*)(ip + (size_t)c * HW);
        const float* wr = wT + (size_t)c * OS + o0;
        #pragma unroll
        for (int u = 0; u < 16; ++u) {
            float wv = wr[u];
            acc[u].x = fmaf(v.x, wv, acc[u].x);
            acc[u].y = fmaf(v.y, wv, acc[u].y);
            acc[u].z = fmaf(v.z, wv, acc[u].z);
            acc[u].w = fmaf(v.w, wv, acc[u].w);
        }
    }
    size_t obase = (size_t)b * Cout * HW + p;
    if (EPI == 0) {
        float4 m = *(const float4*)(mu + p4);
        float4 r = *(const float4*)(rsig + p4);
        #pragma unroll
        for (int u = 0; u < 16; ++u) {
            int o = o0 + u;
            if (o < Cout) {
                float so = S[o], bo = Bb[o];
                float4 ov;
                ov.x = r.x * (acc[u].x - m.x * so) + bo;
                ov.y = r.y * (acc[u].y - m.y * so) + bo;
                ov.z = r.z * (acc[u].z - m.z * so) + bo;
                ov.w = r.w * (acc[u].w - m.w * so) + bo;
                *(float4*)(out + obase + (size_t)o * HW) = ov;
            }
        }
    } else if (EPI == 1) {
        #pragma unroll
        for (int u = 0; u < 16; ++u) {
            int o = o0 + u;
            float bo = Bb[o], sc = scale[o];
            float4 rv = *(const float4*)(res + obase + (size_t)o * HW);
            float4 ov;
            ov.x = rv.x + (acc[u].x + bo) * sc;
            ov.y = rv.y + (acc[u].y + bo) * sc;
            ov.z = rv.z + (acc[u].z + bo) * sc;
            ov.w = rv.w + (acc[u].w + bo) * sc;
            *(float4*)(out + obase + (size_t)o * HW) = ov;
        }
    } else {
        #pragma unroll
        for (int u = 0; u < 16; ++u) {
            int o = o0 + u;
            float sc = scale[o];
            float4 rv = *(const float4*)(res + obase + (size_t)o * HW);
            float4 ov;
            ov.x = rv.x + acc[u].x * sc;
            ov.y = rv.y + acc[u].y * sc;
            ov.z = rv.z + acc[u].z * sc;
            ov.w = rv.w + acc[u].w * sc;
            *(float4*)(out + obase + (size_t)o * HW) = ov;
        }
    }
}

// ---------------------------------------------------------------------------
// Depthwise 3x3 + bias for one head group (q, k, or v), output TRANSPOSED to
// [b][head][px][16].  NORM=true l2-normalizes the fragment (K path).
// ---------------------------------------------------------------------------
template<bool NORM>
__global__ __launch_bounds__(256) void dwconv_t(
    const float* __restrict__ in, const float* __restrict__ dwv,
    const float* __restrict__ bias, float* __restrict__ outt, int cbase)
{
    int t  = blockIdx.x * 256 + threadIdx.x;
    int p4 = t * 4;
    int bh = blockIdx.y;                       // b*NH + head
    int b = bh / NH, head = bh % NH;
    int h = p4 >> 7, wx = p4 & (WD - 1);
    float4 acc[16];
    #pragma unroll
    for (int hd = 0; hd < 16; ++hd) {
        int c = cbase + head * HD + hd;
        const float* ip = in + ((size_t)b * C3 + c) * HW;
        const float* wk = dwv + c * 9;
        float bz = bias[c];
        float a0 = bz, a1 = bz, a2 = bz, a3 = bz;
        #pragma unroll
        for (int ky = 0; ky < 3; ++ky) {
            int hh = h + ky - 1;
            if (hh < 0 || hh >= HT) continue;
            const float* rowp = ip + hh * WD + wx;
            float vm = (wx > 0)      ? rowp[-1] : 0.f;
            float4 v = *(const float4*)rowp;
            float vp = (wx + 4 < WD) ? rowp[4]  : 0.f;
            float w0 = wk[ky*3+0], w1 = wk[ky*3+1], w2 = wk[ky*3+2];
            a0 = fmaf(vm,  w0, a0); a0 = fmaf(v.x, w1, a0); a0 = fmaf(v.y, w2, a0);
            a1 = fmaf(v.x, w0, a1); a1 = fmaf(v.y, w1, a1); a1 = fmaf(v.z, w2, a1);
            a2 = fmaf(v.y, w0, a2); a2 = fmaf(v.z, w1, a2); a2 = fmaf(v.w, w2, a2);
            a3 = fmaf(v.z, w0, a3); a3 = fmaf(v.w, w1, a3); a3 = fmaf(vp,  w2, a3);
        }
        acc[hd] = {a0, a1, a2, a3};
    }
    if (NORM) {
        float n0=0.f, n1=0.f, n2=0.f, n3=0.f;
        #pragma unroll
        for (int hd = 0; hd < 16; ++hd) {
            n0 = fmaf(acc[hd].x, acc[hd].x, n0);
            n1 = fmaf(acc[hd].y, acc[hd].y, n1);
            n2 = fmaf(acc[hd].z, acc[hd].z, n2);
            n3 = fmaf(acc[hd].w, acc[hd].w, n3);
        }
        n0 = 1.f / fmaxf(sqrtf(n0), 1e-12f);
        n1 = 1.f / fmaxf(sqrtf(n1), 1e-12f);
        n2 = 1.f / fmaxf(sqrtf(n2), 1e-12f);
        n3 = 1.f / fmaxf(sqrtf(n3), 1e-12f);
        #pragma unroll
        for (int hd = 0; hd < 16; ++hd) {
            acc[hd].x *= n0; acc[hd].y *= n1; acc[hd].z *= n2; acc[hd].w *= n3;
        }
    }
    float* op = outt + ((size_t)bh * HW + p4) * 16;
#define STORE_PX(pi, comp)                                                    \
    {                                                                         \
        float4 w0 = {acc[ 0].comp, acc[ 1].comp, acc[ 2].comp, acc[ 3].comp}; \
        float4 w1 = {acc[ 4].comp, acc[ 5].comp, acc[ 6].comp, acc[ 7].comp}; \
        float4 w2 = {acc[ 8].comp, acc[ 9].comp, acc[10].comp, acc[11].comp}; \
        float4 w3 = {acc[12].comp, acc[13].comp, acc[14].comp, acc[15].comp}; \
        *(float4*)(op + pi*16 +  0) = w0;                                     \
        *(float4*)(op + pi*16 +  4) = w1;                                     \
        *(float4*)(op + pi*16 +  8) = w2;                                     \
        *(float4*)(op + pi*16 + 12) = w3;                                     \
    }
    STORE_PX(0, x) STORE_PX(1, y) STORE_PX(2, z) STORE_PX(3, w)
#undef STORE_PX
}

// FFN depthwise 3x3 (no bias) fused with exact-GELU gating, 4 pixels/thread.
__global__ __launch_bounds__(256) void dw_gate(
    const float* __restrict__ in, const float* __restrict__ dwv,
    float* __restrict__ out)
{
    int t  = blockIdx.x * 256 + threadIdx.x;
    int p4 = t * 4;
    int bj = blockIdx.y;
    int b = bj / HID, j = bj % HID;
    int h = p4 >> 7, wx = p4 & (WD - 1);
    const float* i1 = in + ((size_t)b * HID2 + j) * HW;
    const float* i2 = i1 + (size_t)HID * HW;
    const float* wk1 = dwv + j * 9;
    const float* wk2 = dwv + (j + HID) * 9;
    float a0=0.f,a1=0.f,a2=0.f,a3=0.f, g0=0.f,g1=0.f,g2=0.f,g3=0.f;
    #pragma unroll
    for (int ky = 0; ky < 3; ++ky) {
        int hh = h + ky - 1;
        if (hh < 0 || hh >= HT) continue;
        const float* r1 = i1 + hh * WD + wx;
        const float* r2 = i2 + hh * WD + wx;
        bool lm = (wx > 0), rp = (wx + 4 < WD);
        float um = lm ? r1[-1] : 0.f;
        float4 u = *(const float4*)r1;
        float up = rp ? r1[4] : 0.f;
        float vm = lm ? r2[-1] : 0.f;
        float4 v = *(const float4*)r2;
        float vp = rp ? r2[4] : 0.f;
        float w10 = wk1[ky*3+0], w11 = wk1[ky*3+1], w12 = wk1[ky*3+2];
        float w20 = wk2[ky*3+0], w21 = wk2[ky*3+1], w22 = wk2[ky*3+2];
        a0 = fmaf(um,  w10, a0); a0 = fmaf(u.x, w11, a0); a0 = fmaf(u.y, w12, a0);
        a1 = fmaf(u.x, w10, a1); a1 = fmaf(u.y, w11, a1); a1 = fmaf(u.z, w12, a1);
        a2 = fmaf(u.y, w10, a2); a2 = fmaf(u.z, w11, a2); a2 = fmaf(u.w, w12, a2);
        a3 = fmaf(u.z, w10, a3); a3 = fmaf(u.w, w11, a3); a3 = fmaf(up,  w12, a3);
        g0 = fmaf(vm,  w20, g0); g0 = fmaf(v.x, w21, g0); g0 = fmaf(v.y, w22, g0);
        g1 = fmaf(v.x, w20, g1); g1 = fmaf(v.y, w21, g1); g1 = fmaf(v.z, w22, g1);
        g2 = fmaf(v.y, w20, g2); g2 = fmaf(v.z, w21, g2); g2 = fmaf(v.w, w22, g2);
        g3 = fmaf(v.z, w20, g3); g3 = fmaf(v.w, w21, g3); g3 = fmaf(vp,  w22, g3);
    }
    const float is2 = 0.70710678118654752f;
    float4 ov;
    ov.x = 0.5f * a0 * (1.f + erff(a0 * is2)) * g0;
    ov.y = 0.5f * a1 * (1.f + erff(a1 * is2)) * g1;
    ov.z = 0.5f * a2 * (1.f + erff(a2 * is2)) * g2;
    ov.w = 0.5f * a3 * (1.f + erff(a3 * is2)) * g3;
    *(float4*)(out + ((size_t)b * HID + j) * HW + p4) = ov;
}

// ---------------------------------------------------------------------------
// Neighborhood attention, LDS v2.
// - K and V staged up-front into SEPARATE plane-major buffers (float4 planes:
//   s[sub][frag]) -> canonical conflict-free dense-float4 ds_read pattern.
// - single __syncthreads; no barrier between passes (reads only).
// - sched_barrier(0) every 4 neighbors bounds ds_read hoisting (register
//   blow-up in v1 spilled to scratch: VGPR 256, 570 MB scratch writes).
// ---------------------------------------------------------------------------
__global__ __launch_bounds__(256) void natten(
    const float* __restrict__ qt, const float* __restrict__ kt,
    const float* __restrict__ vt, const float* __restrict__ rpb,
    const float* __restrict__ temp, float* __restrict__ out)
{
    __shared__ __align__(16) float4 sK[4][NFR];      // 30,976 B
    __shared__ __align__(16) float4 sV[4][NFR];      // 30,976 B
    __shared__ float srpb[169];
    int tid = threadIdx.x;
    int bh = blockIdx.z;
    int b = bh / NH, head = bh % NH;
    float T = temp[head];
    if (tid < 169) srpb[tid] = rpb[head * 169 + tid] * T;

    int i0 = blockIdx.y * 16, j0 = blockIdx.x * 16;
    int r0 = min(max(i0 - 3, 0), HT - LRD);
    int c0 = min(max(j0 - 3, 0), WD - LRD);
    const float4* ktb = (const float4*)(kt + (size_t)bh * HW * 16);
    const float4* vtb = (const float4*)(vt + (size_t)bh * HW * 16);

    // ---- stage K and V (plane-major; sub = channel quad) ----
    #pragma unroll
    for (int sub = 0; sub < 4; ++sub) {
        #pragma unroll
        for (int base = 0; base < NFR; base += 256) {
            int fg = base + tid;
            if (fg < NFR) {
                int fr = fg / LRD, fc = fg - fr * LRD;
                size_t g = (size_t)((r0 + fr) * WD + (c0 + fc)) * 4 + sub;
                sK[sub][fg] = ktb[g];
                sV[sub][fg] = vtb[g];
            }
        }
    }

    int i = i0 + (tid >> 4);
    int j = j0 + (tid & 15);

    // q fragment (pixel-major) + l2 norm + temperature (overlaps staging)
    const float* qp = qt + ((size_t)bh * HW + (size_t)(i * WD + j)) * 16;
    float4 q0 = *(const float4*)(qp + 0);
    float4 q1 = *(const float4*)(qp + 4);
    float4 q2 = *(const float4*)(qp + 8);
    float4 q3 = *(const float4*)(qp + 12);
    float qn = 0.f;
    qn = fmaf(q0.x,q0.x,qn); qn = fmaf(q0.y,q0.y,qn); qn = fmaf(q0.z,q0.z,qn); qn = fmaf(q0.w,q0.w,qn);
    qn = fmaf(q1.x,q1.x,qn); qn = fmaf(q1.y,q1.y,qn); qn = fmaf(q1.z,q1.z,qn); qn = fmaf(q1.w,q1.w,qn);
    qn = fmaf(q2.x,q2.x,qn); qn = fmaf(q2.y,q2.y,qn); qn = fmaf(q2.z,q2.z,qn); qn = fmaf(q2.w,q2.w,qn);
    qn = fmaf(q3.x,q3.x,qn); qn = fmaf(q3.y,q3.y,qn); qn = fmaf(q3.z,q3.z,qn); qn = fmaf(q3.w,q3.w,qn);
    qn = T / fmaxf(sqrtf(qn), 1e-12f);
    q0.x*=qn; q0.y*=qn; q0.z*=qn; q0.w*=qn;
    q1.x*=qn; q1.y*=qn; q1.z*=qn; q1.w*=qn;
    q2.x*=qn; q2.y*=qn; q2.z*=qn; q2.w*=qn;
    q3.x*=qn; q3.y*=qn; q3.z*=qn; q3.w*=qn;

    int ri0 = min(max(i - 3, 0), HT - KK);
    int cj0 = min(max(j - 3, 0), WD - KK);
    int bi0 = i - ri0 + 6, bj0 = j - cj0 + 6;
    int fbase = (ri0 - r0) * LRD + (cj0 - c0);

    __syncthreads();                    // K, V, srpb staged

    // ---- pass 1: scores from LDS K ----
    float s[NNB]; float m = -1e30f;
    #pragma unroll
    for (int o = 0; o < NNB; ++o) {
        int fg = fbase + (o / KK) * LRD + (o % KK);
        float4 k0 = sK[0][fg];
        float4 k1 = sK[1][fg];
        float4 k2 = sK[2][fg];
        float4 k3 = sK[3][fg];
        float d = 0.f;
        d = fmaf(q0.x,k0.x,d); d = fmaf(q0.y,k0.y,d); d = fmaf(q0.z,k0.z,d); d = fmaf(q0.w,k0.w,d);
        d = fmaf(q1.x,k1.x,d); d = fmaf(q1.y,k1.y,d); d = fmaf(q1.z,k1.z,d); d = fmaf(q1.w,k1.w,d);
        d = fmaf(q2.x,k2.x,d); d = fmaf(q2.y,k2.y,d); d = fmaf(q2.z,k2.z,d); d = fmaf(q2.w,k2.w,d);
        d = fmaf(q3.x,k3.x,d); d = fmaf(q3.y,k3.y,d); d = fmaf(q3.z,k3.z,d); d = fmaf(q3.w,k3.w,d);
        float sv = d + srpb[(bi0 - o / KK) * 13 + (bj0 - o % KK)];
        s[o] = sv;
        m = fmaxf(m, sv);
        if ((o & 3) == 3) __builtin_amdgcn_sched_barrier(0);
    }

    // ---- softmax weights ----
    float l = 0.f;
    #pragma unroll
    for (int o = 0; o < NNB; ++o) { float pv = __expf(s[o] - m); s[o] = pv; l += pv; }
    float inv = 1.f / l;

    // ---- pass 2: AV from LDS V ----
    float4 a0 = {0.f,0.f,0.f,0.f}, a1 = a0, a2 = a0, a3 = a0;
    #pragma unroll
    for (int o = 0; o < NNB; ++o) {
        int fg = fbase + (o / KK) * LRD + (o % KK);
        float4 v0 = sV[0][fg];
        float4 v1 = sV[1][fg];
        float4 v2 = sV[2][fg];
        float4 v3 = sV[3][fg];
        float pv = s[o];
        a0.x = fmaf(pv, v0.x, a0.x); a0.y = fmaf(pv, v0.y, a0.y);
        a0.z = fmaf(pv, v0.z, a0.z); a0.w = fmaf(pv, v0.w, a0.w);
        a1.x = fmaf(pv, v1.x, a1.x); a1.y = fmaf(pv, v1.y, a1.y);
        a1.z = fmaf(pv, v1.z, a1.z); a1.w = fmaf(pv, v1.w, a1.w);
        a2.x = fmaf(pv, v2.x, a2.x); a2.y = fmaf(pv, v2.y, a2.y);
        a2.z = fmaf(pv, v2.z, a2.z); a2.w = fmaf(pv, v2.w, a2.w);
        a3.x = fmaf(pv, v3.x, a3.x); a3.y = fmaf(pv, v3.y, a3.y);
        a3.z = fmaf(pv, v3.z, a3.z); a3.w = fmaf(pv, v3.w, a3.w);
        if ((o & 3) == 3) __builtin_amdgcn_sched_barrier(0);
    }
    float* op = out + ((size_t)b * CD + head * HD) * HW + i * WD + j;
    op[(size_t) 0*HW] = a0.x*inv; op[(size_t) 1*HW] = a0.y*inv;
    op[(size_t) 2*HW] = a0.z*inv; op[(size_t) 3*HW] = a0.w*inv;
    op[(size_t) 4*HW] = a1.x*inv; op[(size_t) 5*HW] = a1.y*inv;
    op[(size_t) 6*HW] = a1.z*inv; op[(size_t) 7*HW] = a1.w*inv;
    op[(size_t) 8*HW] = a2.x*inv; op[(size_t) 9*HW] = a2.y*inv;
    op[(size_t)10*HW] = a2.z*inv; op[(size_t)11*HW] = a2.w*inv;
    op[(size_t)12*HW] = a3.x*inv; op[(size_t)13*HW] = a3.y*inv;
    op[(size_t)14*HW] = a3.z*inv; op[(size_t)15*HW] = a3.w*inv;
}

// ---------------------------------------------------------------------------
extern "C" void kernel_launch(void* const* d_in, const int* in_sizes, int n_in,
                              void* d_out, int out_size, void* d_ws, size_t ws_size,
                              hipStream_t stream)
{
    const float* x        = (const float*)d_in[0];
    const float* ln1_w    = (const float*)d_in[1];
    const float* ln1_b    = (const float*)d_in[2];
    const float* qkv_w    = (const float*)d_in[3];
    const float* qkv_b    = (const float*)d_in[4];
    const float* qkv_dw_w = (const float*)d_in[5];
    const float* qkv_dw_b = (const float*)d_in[6];
    const float* rpb      = (const float*)d_in[7];
    const float* temp     = (const float*)d_in[8];
    const float* proj_w   = (const float*)d_in[9];
    const float* proj_b   = (const float*)d_in[10];
    const float* ln2_w    = (const float*)d_in[11];
    const float* ln2_b    = (const float*)d_in[12];
    const float* pin_w    = (const float*)d_in[13];
    const float* dw_w     = (const float*)d_in[14];
    const float* pout_w   = (const float*)d_in[15];
    const float* beta     = (const float*)d_in[16];
    const float* gamma    = (const float*)d_in[17];
    float* out = (float*)d_out;
    float* f   = (float*)d_ws;
    (void)in_sizes; (void)n_in; (void)out_size; (void)ws_size;

    // workspace layout (floats)
    float* W1T = f;                  // 27648
    float* W2T = W1T + 27648;        // 49152
    float* WPT = W2T + 49152;        // 9216
    float* WOT = WPT + 9216;         // 24480
    float* S1  = WOT + 24480;        // 512 each
    float* B1  = S1 + 512;
    float* S2  = B1 + 512;
    float* B2  = S2 + 512;
    float* MU  = B2 + 512;           // 65536
    float* RS  = MU + 65536;         // 65536
    float* A   = f + 262144;
    float* QKV = A;                  // 18,874,368 qkv_pre; later ffn_pre
    float* QT  = A + 18874368;       //  6,291,456 q, transposed [bh][px][16]
    float* KT  = QT + 6291456;       //  6,291,456 K, transposed+normalized
    float* VT  = KT + 6291456;       //  6,291,456 V, transposed
    float* AO  = A + 37748736;       //  6,291,456 attn out; later gated (16.7M)
    float* X2  = A + 54460416;       //  6,291,456 post-attention residual

    // 1. fold LN1/LN2 into conv weights; transpose all conv weights
    prep_weights<<<dim3(2), dim3(256), 0, stream>>>(
        qkv_w, qkv_b, ln1_w, ln1_b, pin_w, ln2_w, ln2_b, proj_w, pout_w,
        W1T, S1, B1, W2T, S2, B2, WPT, WOT);
    // 2. LN1 stats
    ln_stats<<<dim3(64), dim3(256), 0, stream>>>(x, MU, RS);
    // 3. qkv_pre = conv1x1(LN1(x))  [B,288,HW]
    conv1x1<0><<<dim3(18, 64), dim3(256), 0, stream>>>(
        x, W1T, CD, C3, C3, S1, B1, MU, RS, nullptr, nullptr, QKV);
    // 4. depthwise 3x3 + bias; q/k/v all transposed to [bh][px][16] (K normed)
    dwconv_t<false><<<dim3(16, NB_B * NH), dim3(256), 0, stream>>>(
        QKV, qkv_dw_w, qkv_dw_b, QT, 0);
    dwconv_t<true><<<dim3(16, NB_B * NH), dim3(256), 0, stream>>>(
        QKV, qkv_dw_w, qkv_dw_b, KT, CD);
    dwconv_t<false><<<dim3(16, NB_B * NH), dim3(256), 0, stream>>>(
        QKV, qkv_dw_w, qkv_dw_b, VT, 2 * CD);
    // 5. neighborhood attention (LDS v2) -> [B,96,HW]
    natten<<<dim3(8, 8, NB_B * NH), dim3(256), 0, stream>>>(
        QT, KT, VT, rpb, temp, AO);
    // 6. x2 = x + (proj(attn)+proj_b)*beta
    conv1x1<1><<<dim3(6, 64), dim3(256), 0, stream>>>(
        AO, WPT, CD, CD, CD, nullptr, proj_b, nullptr, nullptr, x, beta, X2);
    // 7. LN2 stats
    ln_stats<<<dim3(64), dim3(256), 0, stream>>>(X2, MU, RS);
    // 8. ffn_pre = conv1x1(LN2(x2))  [B,510,HW]
    conv1x1<0><<<dim3(32, 64), dim3(256), 0, stream>>>(
        X2, W2T, CD, HID2, 512, S2, B2, MU, RS, nullptr, nullptr, QKV);
    // 9. gated = gelu(dw(x1)) * dw(x2)  [B,255,HW]
    dw_gate<<<dim3(16, NB_B * HID), dim3(256), 0, stream>>>(QKV, dw_w, AO);
    // 10. out = x2 + pout(gated)*gamma
    conv1x1<2><<<dim3(6, 64), dim3(256), 0, stream>>>(
        AO, WOT, HID, CD, CD, nullptr, nullptr, nullptr, nullptr, X2, gamma, out);
}

// Round 12
// 598.222 us; speedup vs baseline: 1.5066x; 1.3284x over previous
//
#include <hip/hip_runtime.h>
#include <math.h>

// Shapes (fixed for this problem)
#define HT   128
#define WD   128
#define HW   16384      // HT*WD
#define NB_B 4
#define BHW  65536      // NB_B*HW
#define CD   96
#define C3   288
#define NH   6
#define HD   16
#define HID  255
#define HID2 510
#define KK   7
#define NNB  49
// natten LDS tile
#define LRD  22         // halo tile side (16 + 6)
#define NFR  484        // 22*22 fragments

// ---------------------------------------------------------------------------
// Fold LayerNorm affine into the following 1x1 conv, and store weights
// TRANSPOSED (wT[c*OS + o]).  Also transposes proj_w and pout_w.
// ---------------------------------------------------------------------------
__global__ __launch_bounds__(256) void prep_weights(
    const float* __restrict__ qkv_w, const float* __restrict__ qkv_b,
    const float* __restrict__ ln1_w, const float* __restrict__ ln1_b,
    const float* __restrict__ pin_w, const float* __restrict__ ln2_w,
    const float* __restrict__ ln2_b,
    const float* __restrict__ proj_w, const float* __restrict__ pout_w,
    float* __restrict__ w1t, float* __restrict__ s1, float* __restrict__ b1,
    float* __restrict__ w2t, float* __restrict__ s2, float* __restrict__ b2,
    float* __restrict__ wpt, float* __restrict__ wot)
{
    int o = blockIdx.x * 256 + threadIdx.x;          // [0, 512)
    if (o < C3) {
        float s = 0.f, bb = qkv_b[o];
        for (int c = 0; c < CD; ++c) {
            float wv = qkv_w[o*CD+c] * ln1_w[c];
            w1t[(size_t)c * C3 + o] = wv;
            s += wv;
            bb += qkv_w[o*CD+c] * ln1_b[c];
        }
        s1[o] = s; b1[o] = bb;
    }
    if (o < HID2) {
        float s = 0.f, bb = 0.f;                     // pin conv has no bias
        for (int c = 0; c < CD; ++c) {
            float wv = pin_w[o*CD+c] * ln2_w[c];
            w2t[(size_t)c * 512 + o] = wv;
            s += wv;
            bb += pin_w[o*CD+c] * ln2_b[c];
        }
        s2[o] = s; b2[o] = bb;
    } else if (o < 512) {                            // pad cols 510/511
        for (int c = 0; c < CD; ++c) w2t[(size_t)c * 512 + o] = 0.f;
        s2[o] = 0.f; b2[o] = 0.f;
    }
    if (o < CD) {
        for (int c = 0; c < CD; ++c)
            wpt[(size_t)c * CD + o] = proj_w[o*CD + c];
        for (int c = 0; c < HID; ++c)
            wot[(size_t)c * CD + o] = pout_w[o*HID + c];
    }
}

// Per-pixel LayerNorm stats (biased variance, eps 1e-5), 4 pixels/thread.
__global__ __launch_bounds__(256) void ln_stats(
    const float* __restrict__ x, float* __restrict__ mu, float* __restrict__ rsig)
{
    int t  = blockIdx.x * 256 + threadIdx.x;
    int p4 = t * 4;
    int b = p4 >> 14, p = p4 & (HW - 1);
    const float* xp = x + (size_t)b * CD * HW + p;
    float4 s = {0.f,0.f,0.f,0.f}, s2 = {0.f,0.f,0.f,0.f};
    #pragma unroll 4
    for (int c = 0; c < CD; ++c) {
        float4 v = *(const float4*)(xp + (size_t)c * HW);
        s.x += v.x; s.y += v.y; s.z += v.z; s.w += v.w;
        s2.x = fmaf(v.x, v.x, s2.x); s2.y = fmaf(v.y, v.y, s2.y);
        s2.z = fmaf(v.z, v.z, s2.z); s2.w = fmaf(v.w, v.w, s2.w);
    }
    const float inv = 1.f / CD;
    float4 m, r;
    m.x = s.x*inv; m.y = s.y*inv; m.z = s.z*inv; m.w = s.w*inv;
    r.x = rsqrtf(s2.x*inv - m.x*m.x + 1e-5f);
    r.y = rsqrtf(s2.y*inv - m.y*m.y + 1e-5f);
    r.z = rsqrtf(s2.z*inv - m.z*m.z + 1e-5f);
    r.w = rsqrtf(s2.w*inv - m.w*m.w + 1e-5f);
    *(float4*)(mu + p4)   = m;
    *(float4*)(rsig + p4) = r;
}

// ---------------------------------------------------------------------------
// 1x1 conv (vector ALU GEMM). 4 pixels x 16 couts / thread.
// ---------------------------------------------------------------------------
template<int EPI>
__global__ __launch_bounds__(256) void conv1x1(
    const float* __restrict__ in, const float* __restrict__ wT,
    int Cin, int Cout, int OS,
    const float* __restrict__ S, const float* __restrict__ Bb,
    const float* __restrict__ mu, const float* __restrict__ rsig,
    const float* __restrict__ res, const float* __restrict__ scale,
    float* __restrict__ out)
{
    int t  = blockIdx.y * 256 + threadIdx.x;
    int p4 = t * 4;
    int o0 = blockIdx.x * 16;
    int b = p4 >> 14, p = p4 & (HW - 1);
    const float* ip = in + (size_t)b * Cin * HW + p;
    float4 acc[16];
    #pragma unroll
    for (int u = 0; u < 16; ++u) acc[u] = {0.f,0.f,0.f,0.f};
    #pragma unroll 2
    for (int c = 0; c < Cin; ++c) {
        float4 v = *(const float4*)(ip + (size_t)c * HW);
        const float* wr = wT + (size_t)c * OS + o0;
        #pragma unroll
        for (int u = 0; u < 16; ++u) {
            float wv = wr[u];
            acc[u].x = fmaf(v.x, wv, acc[u].x);
            acc[u].y = fmaf(v.y, wv, acc[u].y);
            acc[u].z = fmaf(v.z, wv, acc[u].z);
            acc[u].w = fmaf(v.w, wv, acc[u].w);
        }
    }
    size_t obase = (size_t)b * Cout * HW + p;
    if (EPI == 0) {
        float4 m = *(const float4*)(mu + p4);
        float4 r = *(const float4*)(rsig + p4);
        #pragma unroll
        for (int u = 0; u < 16; ++u) {
            int o = o0 + u;
            if (o < Cout) {
                float so = S[o], bo = Bb[o];
                float4 ov;
                ov.x = r.x * (acc[u].x - m.x * so) + bo;
                ov.y = r.y * (acc[u].y - m.y * so) + bo;
                ov.z = r.z * (acc[u].z - m.z * so) + bo;
                ov.w = r.w * (acc[u].w - m.w * so) + bo;
                *(float4*)(out + obase + (size_t)o * HW) = ov;
            }
        }
    } else if (EPI == 1) {
        #pragma unroll
        for (int u = 0; u < 16; ++u) {
            int o = o0 + u;
            float bo = Bb[o], sc = scale[o];
            float4 rv = *(const float4*)(res + obase + (size_t)o * HW);
            float4 ov;
            ov.x = rv.x + (acc[u].x + bo) * sc;
            ov.y = rv.y + (acc[u].y + bo) * sc;
            ov.z = rv.z + (acc[u].z + bo) * sc;
            ov.w = rv.w + (acc[u].w + bo) * sc;
            *(float4*)(out + obase + (size_t)o * HW) = ov;
        }
    } else {
        #pragma unroll
        for (int u = 0; u < 16; ++u) {
            int o = o0 + u;
            float sc = scale[o];
            float4 rv = *(const float4*)(res + obase + (size_t)o * HW);
            float4 ov;
            ov.x = rv.x + acc[u].x * sc;
            ov.y = rv.y + acc[u].y * sc;
            ov.z = rv.z + acc[u].z * sc;
            ov.w = rv.w + acc[u].w * sc;
            *(float4*)(out + obase + (size_t)o * HW) = ov;
        }
    }
}

// ---------------------------------------------------------------------------
// Depthwise 3x3 + bias for one head group (q, k, or v), output TRANSPOSED to
// [b][head][px][16].  NORM=true l2-normalizes the fragment (K path).
// ---------------------------------------------------------------------------
template<bool NORM>
__global__ __launch_bounds__(256) void dwconv_t(
    const float* __restrict__ in, const float* __restrict__ dwv,
    const float* __restrict__ bias, float* __restrict__ outt, int cbase)
{
    int t  = blockIdx.x * 256 + threadIdx.x;
    int p4 = t * 4;
    int bh = blockIdx.y;                       // b*NH + head
    int b = bh / NH, head = bh % NH;
    int h = p4 >> 7, wx = p4 & (WD - 1);
    float4 acc[16];
    #pragma unroll
    for (int hd = 0; hd < 16; ++hd) {
        int c = cbase + head * HD + hd;
        const float* ip = in + ((size_t)b * C3 + c) * HW;
        const float* wk = dwv + c * 9;
        float bz = bias[c];
        float a0 = bz, a1 = bz, a2 = bz, a3 = bz;
        #pragma unroll
        for (int ky = 0; ky < 3; ++ky) {
            int hh = h + ky - 1;
            if (hh < 0 || hh >= HT) continue;
            const float* rowp = ip + hh * WD + wx;
            float vm = (wx > 0)      ? rowp[-1] : 0.f;
            float4 v = *(const float4*)rowp;
            float vp = (wx + 4 < WD) ? rowp[4]  : 0.f;
            float w0 = wk[ky*3+0], w1 = wk[ky*3+1], w2 = wk[ky*3+2];
            a0 = fmaf(vm,  w0, a0); a0 = fmaf(v.x, w1, a0); a0 = fmaf(v.y, w2, a0);
            a1 = fmaf(v.x, w0, a1); a1 = fmaf(v.y, w1, a1); a1 = fmaf(v.z, w2, a1);
            a2 = fmaf(v.y, w0, a2); a2 = fmaf(v.z, w1, a2); a2 = fmaf(v.w, w2, a2);
            a3 = fmaf(v.z, w0, a3); a3 = fmaf(v.w, w1, a3); a3 = fmaf(vp,  w2, a3);
        }
        acc[hd] = {a0, a1, a2, a3};
    }
    if (NORM) {
        float n0=0.f, n1=0.f, n2=0.f, n3=0.f;
        #pragma unroll
        for (int hd = 0; hd < 16; ++hd) {
            n0 = fmaf(acc[hd].x, acc[hd].x, n0);
            n1 = fmaf(acc[hd].y, acc[hd].y, n1);
            n2 = fmaf(acc[hd].z, acc[hd].z, n2);
            n3 = fmaf(acc[hd].w, acc[hd].w, n3);
        }
        n0 = 1.f / fmaxf(sqrtf(n0), 1e-12f);
        n1 = 1.f / fmaxf(sqrtf(n1), 1e-12f);
        n2 = 1.f / fmaxf(sqrtf(n2), 1e-12f);
        n3 = 1.f / fmaxf(sqrtf(n3), 1e-12f);
        #pragma unroll
        for (int hd = 0; hd < 16; ++hd) {
            acc[hd].x *= n0; acc[hd].y *= n1; acc[hd].z *= n2; acc[hd].w *= n3;
        }
    }
    float* op = outt + ((size_t)bh * HW + p4) * 16;
#define STORE_PX(pi, comp)                                                    \
    {                                                                         \
        float4 w0 = {acc[ 0].comp, acc[ 1].comp, acc[ 2].comp, acc[ 3].comp}; \
        float4 w1 = {acc[ 4].comp, acc[ 5].comp, acc[ 6].comp, acc[ 7].comp}; \
        float4 w2 = {acc[ 8].comp, acc[ 9].comp, acc[10].comp, acc[11].comp}; \
        float4 w3 = {acc[12].comp, acc[13].comp, acc[14].comp, acc[15].comp}; \
        *(float4*)(op + pi*16 +  0) = w0;                                     \
        *(float4*)(op + pi*16 +  4) = w1;                                     \
        *(float4*)(op + pi*16 +  8) = w2;                                     \
        *(float4*)(op + pi*16 + 12) = w3;                                     \
    }
    STORE_PX(0, x) STORE_PX(1, y) STORE_PX(2, z) STORE_PX(3, w)
#undef STORE_PX
}

// FFN depthwise 3x3 (no bias) fused with exact-GELU gating, 4 pixels/thread.
__global__ __launch_bounds__(256) void dw_gate(
    const float* __restrict__ in, const float* __restrict__ dwv,
    float* __restrict__ out)
{
    int t  = blockIdx.x * 256 + threadIdx.x;
    int p4 = t * 4;
    int bj = blockIdx.y;
    int b = bj / HID, j = bj % HID;
    int h = p4 >> 7, wx = p4 & (WD - 1);
    const float* i1 = in + ((size_t)b * HID2 + j) * HW;
    const float* i2 = i1 + (size_t)HID * HW;
    const float* wk1 = dwv + j * 9;
    const float* wk2 = dwv + (j + HID) * 9;
    float a0=0.f,a1=0.f,a2=0.f,a3=0.f, g0=0.f,g1=0.f,g2=0.f,g3=0.f;
    #pragma unroll
    for (int ky = 0; ky < 3; ++ky) {
        int hh = h + ky - 1;
        if (hh < 0 || hh >= HT) continue;
        const float* r1 = i1 + hh * WD + wx;
        const float* r2 = i2 + hh * WD + wx;
        bool lm = (wx > 0), rp = (wx + 4 < WD);
        float um = lm ? r1[-1] : 0.f;
        float4 u = *(const float4*)r1;
        float up = rp ? r1[4] : 0.f;
        float vm = lm ? r2[-1] : 0.f;
        float4 v = *(const float4*)r2;
        float vp = rp ? r2[4] : 0.f;
        float w10 = wk1[ky*3+0], w11 = wk1[ky*3+1], w12 = wk1[ky*3+2];
        float w20 = wk2[ky*3+0], w21 = wk2[ky*3+1], w22 = wk2[ky*3+2];
        a0 = fmaf(um,  w10, a0); a0 = fmaf(u.x, w11, a0); a0 = fmaf(u.y, w12, a0);
        a1 = fmaf(u.x, w10, a1); a1 = fmaf(u.y, w11, a1); a1 = fmaf(u.z, w12, a1);
        a2 = fmaf(u.y, w10, a2); a2 = fmaf(u.z, w11, a2); a2 = fmaf(u.w, w12, a2);
        a3 = fmaf(u.z, w10, a3); a3 = fmaf(u.w, w11, a3); a3 = fmaf(up,  w12, a3);
        g0 = fmaf(vm,  w20, g0); g0 = fmaf(v.x, w21, g0); g0 = fmaf(v.y, w22, g0);
        g1 = fmaf(v.x, w20, g1); g1 = fmaf(v.y, w21, g1); g1 = fmaf(v.z, w22, g1);
        g2 = fmaf(v.y, w20, g2); g2 = fmaf(v.z, w21, g2); g2 = fmaf(v.w, w22, g2);
        g3 = fmaf(v.z, w20, g3); g3 = fmaf(v.w, w21, g3); g3 = fmaf(vp,  w22, g3);
    }
    const float is2 = 0.70710678118654752f;
    float4 ov;
    ov.x = 0.5f * a0 * (1.f + erff(a0 * is2)) * g0;
    ov.y = 0.5f * a1 * (1.f + erff(a1 * is2)) * g1;
    ov.z = 0.5f * a2 * (1.f + erff(a2 * is2)) * g2;
    ov.w = 0.5f * a3 * (1.f + erff(a3 * is2)) * g3;
    *(float4*)(out + ((size_t)b * HID + j) * HW + p4) = ov;
}

// ---------------------------------------------------------------------------
// Neighborhood attention, LDS v3: single-pass ONLINE softmax.
// v2 post-mortem: VGPR 256 + ~1.3KB/thread scratch persisted because the two
// fully-unrolled 49-iter LDS passes kept s[49]+q+acc live across the whole
// span.  v3 removes s[] entirely: per neighbor read K-frag + V-frag from LDS
// and update running (m, l, acc) — loop-carried state is 18 floats, transient
// 32.  unroll 2 bounds prefetch.  Plane-major LDS layout kept (coalesced
// staging, dense float4 reads).
// ---------------------------------------------------------------------------
__global__ __launch_bounds__(256) void natten(
    const float* __restrict__ qt, const float* __restrict__ kt,
    const float* __restrict__ vt, const float* __restrict__ rpb,
    const float* __restrict__ temp, float* __restrict__ out)
{
    __shared__ __align__(16) float4 sK[4][NFR];      // 30,976 B
    __shared__ __align__(16) float4 sV[4][NFR];      // 30,976 B
    __shared__ float srpb[169];
    int tid = threadIdx.x;
    int bh = blockIdx.z;
    int b = bh / NH, head = bh % NH;
    float T = temp[head];
    if (tid < 169) srpb[tid] = rpb[head * 169 + tid] * T;

    int i0 = blockIdx.y * 16, j0 = blockIdx.x * 16;
    int r0 = min(max(i0 - 3, 0), HT - LRD);
    int c0 = min(max(j0 - 3, 0), WD - LRD);
    const float4* ktb = (const float4*)(kt + (size_t)bh * HW * 16);
    const float4* vtb = (const float4*)(vt + (size_t)bh * HW * 16);

    // ---- stage K and V (plane-major; sub = channel quad) ----
    #pragma unroll
    for (int sub = 0; sub < 4; ++sub) {
        #pragma unroll
        for (int base = 0; base < NFR; base += 256) {
            int fg = base + tid;
            if (fg < NFR) {
                int fr = fg / LRD, fc = fg - fr * LRD;
                size_t g = (size_t)((r0 + fr) * WD + (c0 + fc)) * 4 + sub;
                sK[sub][fg] = ktb[g];
                sV[sub][fg] = vtb[g];
            }
        }
    }

    int i = i0 + (tid >> 4);
    int j = j0 + (tid & 15);

    // q fragment (pixel-major) + l2 norm + temperature (overlaps staging)
    const float* qp = qt + ((size_t)bh * HW + (size_t)(i * WD + j)) * 16;
    float4 q0 = *(const float4*)(qp + 0);
    float4 q1 = *(const float4*)(qp + 4);
    float4 q2 = *(const float4*)(qp + 8);
    float4 q3 = *(const float4*)(qp + 12);
    float qn = 0.f;
    qn = fmaf(q0.x,q0.x,qn); qn = fmaf(q0.y,q0.y,qn); qn = fmaf(q0.z,q0.z,qn); qn = fmaf(q0.w,q0.w,qn);
    qn = fmaf(q1.x,q1.x,qn); qn = fmaf(q1.y,q1.y,qn); qn = fmaf(q1.z,q1.z,qn); qn = fmaf(q1.w,q1.w,qn);
    qn = fmaf(q2.x,q2.x,qn); qn = fmaf(q2.y,q2.y,qn); qn = fmaf(q2.z,q2.z,qn); qn = fmaf(q2.w,q2.w,qn);
    qn = fmaf(q3.x,q3.x,qn); qn = fmaf(q3.y,q3.y,qn); qn = fmaf(q3.z,q3.z,qn); qn = fmaf(q3.w,q3.w,qn);
    qn = T / fmaxf(sqrtf(qn), 1e-12f);
    q0.x*=qn; q0.y*=qn; q0.z*=qn; q0.w*=qn;
    q1.x*=qn; q1.y*=qn; q1.z*=qn; q1.w*=qn;
    q2.x*=qn; q2.y*=qn; q2.z*=qn; q2.w*=qn;
    q3.x*=qn; q3.y*=qn; q3.z*=qn; q3.w*=qn;

    int ri0 = min(max(i - 3, 0), HT - KK);
    int cj0 = min(max(j - 3, 0), WD - KK);
    int bi0 = i - ri0 + 6, bj0 = j - cj0 + 6;
    int fbase = (ri0 - r0) * LRD + (cj0 - c0);

    __syncthreads();                    // K, V, srpb staged

    // ---- single pass: online softmax-weighted accumulation ----
    float m = -1e30f, l = 0.f;
    float4 a0 = {0.f,0.f,0.f,0.f}, a1 = a0, a2 = a0, a3 = a0;
    #pragma unroll 2
    for (int o = 0; o < NNB; ++o) {
        int fg = fbase + (o / KK) * LRD + (o % KK);
        float4 k0 = sK[0][fg];
        float4 k1 = sK[1][fg];
        float4 k2 = sK[2][fg];
        float4 k3 = sK[3][fg];
        float4 v0 = sV[0][fg];
        float4 v1 = sV[1][fg];
        float4 v2 = sV[2][fg];
        float4 v3 = sV[3][fg];
        float d = 0.f;
        d = fmaf(q0.x,k0.x,d); d = fmaf(q0.y,k0.y,d); d = fmaf(q0.z,k0.z,d); d = fmaf(q0.w,k0.w,d);
        d = fmaf(q1.x,k1.x,d); d = fmaf(q1.y,k1.y,d); d = fmaf(q1.z,k1.z,d); d = fmaf(q1.w,k1.w,d);
        d = fmaf(q2.x,k2.x,d); d = fmaf(q2.y,k2.y,d); d = fmaf(q2.z,k2.z,d); d = fmaf(q2.w,k2.w,d);
        d = fmaf(q3.x,k3.x,d); d = fmaf(q3.y,k3.y,d); d = fmaf(q3.z,k3.z,d); d = fmaf(q3.w,k3.w,d);
        float sv = d + srpb[(bi0 - o / KK) * 13 + (bj0 - o % KK)];
        float mn = fmaxf(m, sv);
        float c  = __expf(m - mn);      // 0 on first iter (m = -1e30)
        float p  = __expf(sv - mn);
        l = fmaf(l, c, p);
        m = mn;
        a0.x = fmaf(a0.x, c, p * v0.x); a0.y = fmaf(a0.y, c, p * v0.y);
        a0.z = fmaf(a0.z, c, p * v0.z); a0.w = fmaf(a0.w, c, p * v0.w);
        a1.x = fmaf(a1.x, c, p * v1.x); a1.y = fmaf(a1.y, c, p * v1.y);
        a1.z = fmaf(a1.z, c, p * v1.z); a1.w = fmaf(a1.w, c, p * v1.w);
        a2.x = fmaf(a2.x, c, p * v2.x); a2.y = fmaf(a2.y, c, p * v2.y);
        a2.z = fmaf(a2.z, c, p * v2.z); a2.w = fmaf(a2.w, c, p * v2.w);
        a3.x = fmaf(a3.x, c, p * v3.x); a3.y = fmaf(a3.y, c, p * v3.y);
        a3.z = fmaf(a3.z, c, p * v3.z); a3.w = fmaf(a3.w, c, p * v3.w);
    }
    float inv = 1.f / l;
    float* op = out + ((size_t)b * CD + head * HD) * HW + i * WD + j;
    op[(size_t) 0*HW] = a0.x*inv; op[(size_t) 1*HW] = a0.y*inv;
    op[(size_t) 2*HW] = a0.z*inv; op[(size_t) 3*HW] = a0.w*inv;
    op[(size_t) 4*HW] = a1.x*inv; op[(size_t) 5*HW] = a1.y*inv;
    op[(size_t) 6*HW] = a1.z*inv; op[(size_t) 7*HW] = a1.w*inv;
    op[(size_t) 8*HW] = a2.x*inv; op[(size_t) 9*HW] = a2.y*inv;
    op[(size_t)10*HW] = a2.z*inv; op[(size_t)11*HW] = a2.w*inv;
    op[(size_t)12*HW] = a3.x*inv; op[(size_t)13*HW] = a3.y*inv;
    op[(size_t)14*HW] = a3.z*inv; op[(size_t)15*HW] = a3.w*inv;
}

// ---------------------------------------------------------------------------
extern "C" void kernel_launch(void* const* d_in, const int* in_sizes, int n_in,
                              void* d_out, int out_size, void* d_ws, size_t ws_size,
                              hipStream_t stream)
{
    const float* x        = (const float*)d_in[0];
    const float* ln1_w    = (const float*)d_in[1];
    const float* ln1_b    = (const float*)d_in[2];
    const float* qkv_w    = (const float*)d_in[3];
    const float* qkv_b    = (const float*)d_in[4];
    const float* qkv_dw_w = (const float*)d_in[5];
    const float* qkv_dw_b = (const float*)d_in[6];
    const float* rpb      = (const float*)d_in[7];
    const float* temp     = (const float*)d_in[8];
    const float* proj_w   = (const float*)d_in[9];
    const float* proj_b   = (const float*)d_in[10];
    const float* ln2_w    = (const float*)d_in[11];
    const float* ln2_b    = (const float*)d_in[12];
    const float* pin_w    = (const float*)d_in[13];
    const float* dw_w     = (const float*)d_in[14];
    const float* pout_w   = (const float*)d_in[15];
    const float* beta     = (const float*)d_in[16];
    const float* gamma    = (const float*)d_in[17];
    float* out = (float*)d_out;
    float* f   = (float*)d_ws;
    (void)in_sizes; (void)n_in; (void)out_size; (void)ws_size;

    // workspace layout (floats)
    float* W1T = f;                  // 27648
    float* W2T = W1T + 27648;        // 49152
    float* WPT = W2T + 49152;        // 9216
    float* WOT = WPT + 9216;         // 24480
    float* S1  = WOT + 24480;        // 512 each
    float* B1  = S1 + 512;
    float* S2  = B1 + 512;
    float* B2  = S2 + 512;
    float* MU  = B2 + 512;           // 65536
    float* RS  = MU + 65536;         // 65536
    float* A   = f + 262144;
    float* QKV = A;                  // 18,874,368 qkv_pre; later ffn_pre
    float* QT  = A + 18874368;       //  6,291,456 q, transposed [bh][px][16]
    float* KT  = QT + 6291456;       //  6,291,456 K, transposed+normalized
    float* VT  = KT + 6291456;       //  6,291,456 V, transposed
    float* AO  = A + 37748736;       //  6,291,456 attn out; later gated (16.7M)
    float* X2  = A + 54460416;       //  6,291,456 post-attention residual

    // 1. fold LN1/LN2 into conv weights; transpose all conv weights
    prep_weights<<<dim3(2), dim3(256), 0, stream>>>(
        qkv_w, qkv_b, ln1_w, ln1_b, pin_w, ln2_w, ln2_b, proj_w, pout_w,
        W1T, S1, B1, W2T, S2, B2, WPT, WOT);
    // 2. LN1 stats
    ln_stats<<<dim3(64), dim3(256), 0, stream>>>(x, MU, RS);
    // 3. qkv_pre = conv1x1(LN1(x))  [B,288,HW]
    conv1x1<0><<<dim3(18, 64), dim3(256), 0, stream>>>(
        x, W1T, CD, C3, C3, S1, B1, MU, RS, nullptr, nullptr, QKV);
    // 4. depthwise 3x3 + bias; q/k/v all transposed to [bh][px][16] (K normed)
    dwconv_t<false><<<dim3(16, NB_B * NH), dim3(256), 0, stream>>>(
        QKV, qkv_dw_w, qkv_dw_b, QT, 0);
    dwconv_t<true><<<dim3(16, NB_B * NH), dim3(256), 0, stream>>>(
        QKV, qkv_dw_w, qkv_dw_b, KT, CD);
    dwconv_t<false><<<dim3(16, NB_B * NH), dim3(256), 0, stream>>>(
        QKV, qkv_dw_w, qkv_dw_b, VT, 2 * CD);
    // 5. neighborhood attention (LDS v3, online softmax) -> [B,96,HW]
    natten<<<dim3(8, 8, NB_B * NH), dim3(256), 0, stream>>>(
        QT, KT, VT, rpb, temp, AO);
    // 6. x2 = x + (proj(attn)+proj_b)*beta
    conv1x1<1><<<dim3(6, 64), dim3(256), 0, stream>>>(
        AO, WPT, CD, CD, CD, nullptr, proj_b, nullptr, nullptr, x, beta, X2);
    // 7. LN2 stats
    ln_stats<<<dim3(64), dim3(256), 0, stream>>>(X2, MU, RS);
    // 8. ffn_pre = conv1x1(LN2(x2))  [B,510,HW]
    conv1x1<0><<<dim3(32, 64), dim3(256), 0, stream>>>(
        X2, W2T, CD, HID2, 512, S2, B2, MU, RS, nullptr, nullptr, QKV);
    // 9. gated = gelu(dw(x1)) * dw(x2)  [B,255,HW]
    dw_gate<<<dim3(16, NB_B * HID), dim3(256), 0, stream>>>(QKV, dw_w, AO);
    // 10. out = x2 + pout(gated)*gamma
    conv1x1<2><<<dim3(6, 64), dim3(256), 0, stream>>>(
        AO, WOT, HID, CD, CD, nullptr, nullptr, nullptr, nullptr, X2, gamma, out);
}